// Round 4
// baseline (269.969 us; speedup 1.0000x reference)
//
#include <hip/hip_runtime.h>
#include <math.h>

#define N_PTS   16384
#define F_DIM   64
#define K_BINS  32
#define C_DIM   128
#define FK      2048      // F*K
#define CP      144       // padded c-rows in Yt: [y0..y127, ysq, 1, zeros...]
#define CW      132       // W row stride: [w0..w127, S1, B, pad0, pad0]
#define EPS_F   1e-8f

typedef _Float16 f16x8 __attribute__((ext_vector_type(8)));
typedef float    f32x4 __attribute__((ext_vector_type(4)));

static __device__ inline unsigned pack_h2(float a, float b) {
    union { _Float16 h[2]; unsigned u; } x;
    x.h[0] = (_Float16)a; x.h[1] = (_Float16)b;
    return x.u;
}

// ---------------------------------------------------------------------------
// K0: build Yt[c][n] fp16, c-rows: 0..127 = Y^T, 128 = y_sq, 129 = 1.0,
//     130..143 = 0. One block per 64 n.
// ---------------------------------------------------------------------------
__global__ __launch_bounds__(256) void build_yt_k(const float* __restrict__ Y,
                                                  _Float16* __restrict__ Yt) {
    __shared__ __align__(16) float Yl[64][132];
    __shared__ float ysql[64];
    const int t  = threadIdx.x;
    const int n0 = blockIdx.x * 64;
    const int nl = t >> 5;        // 0..7
    const int c4 = t & 31;
#pragma unroll
    for (int p = 0; p < 8; ++p) {
        const int n = p * 8 + nl;
        const float4 v = reinterpret_cast<const float4*>(Y + (size_t)(n0 + n) * C_DIM)[c4];
        reinterpret_cast<float4*>(Yl[n])[c4] = v;
        float sq = v.x * v.x + v.y * v.y + v.z * v.z + v.w * v.w;
#pragma unroll
        for (int m = 16; m >= 1; m >>= 1) sq += __shfl_xor(sq, m, 64);
        if (c4 == 0) ysql[n] = sq;
    }
    __syncthreads();
    unsigned* YtU = (unsigned*)Yt;              // row stride N/2 dwords
    const int nd0 = n0 >> 1;
    const int n2  = t & 31;
    const int rr  = t >> 5;
#pragma unroll
    for (int p = 0; p < 16; ++p) {
        const int c = p * 8 + rr;
        YtU[(size_t)c * (N_PTS / 2) + nd0 + n2] = pack_h2(Yl[2 * n2][c], Yl[2 * n2 + 1][c]);
    }
    if (t < 32) {
        YtU[(size_t)128 * (N_PTS / 2) + nd0 + t] = pack_h2(ysql[2 * t], ysql[2 * t + 1]);
    } else if (t < 64) {
        YtU[(size_t)129 * (N_PTS / 2) + nd0 + (t - 32)] = 0x3C003C00u;  // (1.0h, 1.0h)
    }
    for (int idx = t; idx < 14 * 32; idx += 256) {
        YtU[(size_t)(130 + (idx >> 5)) * (N_PTS / 2) + nd0 + (idx & 31)] = 0u;
    }
}

// ---------------------------------------------------------------------------
// K1: split-K MFMA GEMM, no LDS, no barriers, explicit 2-deep register
// software pipeline (unrolled x2 so buffers never copy).
//   wpart[ch][fk][c] = sum_{n in chunk} M[n][fk] * Yt[c][n]
// Block 256 thr = 4 waves; block owns 64 fk (wave w: one 16-fk m-tile);
// 9 c-tiles of 16 cover the 144 padded c-rows. Grid 32 x nchunk = 1024
// blocks -> 4 blocks/CU; VGPR ~150 -> 3 res. Per 32-n step: 8 scalar A
// loads (16-lane x 64B segments, 4 quad-rows/cacheline-dense; M read once
// from HBM) + 9 x 16B B loads (Yt, L2-resident) + 9 MFMA.
// ---------------------------------------------------------------------------
__global__ __launch_bounds__(256) void gemm_k(const float* __restrict__ M,
                                              const _Float16* __restrict__ Yt,
                                              float* __restrict__ wpart,
                                              int cn) {
    const int t    = threadIdx.x;
    const int fk0  = blockIdx.x * 64;
    const int ch   = blockIdx.y;
    const int n0   = ch * cn;
    const int w    = t >> 6;
    const int l    = t & 63;
    const int quad = l >> 4;
    const int cl   = l & 15;
    const int fkA  = fk0 + w * 16 + cl;     // this wave's m-tile row for lane
    const _Float16* yt = Yt + (size_t)cl * N_PTS;
    const float*    mp = M + fkA;

    f32x4 acc[9] = {};
    f16x8 b0[9], b1[9];
    float a0r[8], a1r[8];

    int nbase = n0 + quad * 8;
    // prologue: load step 0 into buf0
#pragma unroll
    for (int ct = 0; ct < 9; ++ct)
        b0[ct] = *reinterpret_cast<const f16x8*>(yt + (size_t)(ct * 16) * N_PTS + nbase);
#pragma unroll
    for (int j = 0; j < 8; ++j)
        a0r[j] = mp[(size_t)(nbase + j) * FK];

    for (int nb = 0; nb < cn; nb += 64) {
        // prefetch step nb+32 into buf1 (always exists: cn multiple of 64)
        const int nb1 = nbase + 32;
#pragma unroll
        for (int ct = 0; ct < 9; ++ct)
            b1[ct] = *reinterpret_cast<const f16x8*>(yt + (size_t)(ct * 16) * N_PTS + nb1);
#pragma unroll
        for (int j = 0; j < 8; ++j)
            a1r[j] = mp[(size_t)(nb1 + j) * FK];
        // compute on buf0
        {
            f16x8 a;
#pragma unroll
            for (int j = 0; j < 8; ++j) a[j] = (_Float16)a0r[j];
#pragma unroll
            for (int ct = 0; ct < 9; ++ct)
                acc[ct] = __builtin_amdgcn_mfma_f32_16x16x32_f16(a, b0[ct], acc[ct], 0, 0, 0);
        }
        // prefetch step nb+64 into buf0
        const int nb2 = nbase + 64;
        if (nb + 64 < cn) {
#pragma unroll
            for (int ct = 0; ct < 9; ++ct)
                b0[ct] = *reinterpret_cast<const f16x8*>(yt + (size_t)(ct * 16) * N_PTS + nb2);
#pragma unroll
            for (int j = 0; j < 8; ++j)
                a0r[j] = mp[(size_t)(nb2 + j) * FK];
        }
        // compute on buf1
        {
            f16x8 a;
#pragma unroll
            for (int j = 0; j < 8; ++j) a[j] = (_Float16)a1r[j];
#pragma unroll
            for (int ct = 0; ct < 9; ++ct)
                acc[ct] = __builtin_amdgcn_mfma_f32_16x16x32_f16(a, b1[ct], acc[ct], 0, 0, 0);
        }
        nbase = nb2;
    }

    // D layout: col(c) = lane&15, row(fk) = quad*4 + reg
    float* wp = wpart + (size_t)ch * FK * CW;
#pragma unroll
    for (int ct = 0; ct < 9; ++ct) {
        const int c = ct * 16 + cl;
        if (c < CW) {
#pragma unroll
            for (int r = 0; r < 4; ++r) {
                const int fk = fk0 + w * 16 + quad * 4 + r;
                wp[(size_t)fk * CW + c] = acc[ct][r];
            }
        }
    }
}

// ---------------------------------------------------------------------------
// R1: chunk reduction wpart -> W. 528 blocks x 128 thr, 4-way ILP over chunks.
// ---------------------------------------------------------------------------
__global__ __launch_bounds__(128) void reduce_w_k(const float* __restrict__ wpart,
                                                  float* __restrict__ W, int nchunk) {
    const int idx = blockIdx.x * 128 + threadIdx.x;   // float4 index, grid exact
    const float4* src = reinterpret_cast<const float4*>(wpart);
    const size_t cs = (size_t)FK * CW / 4;
    float4 s0 = make_float4(0.f, 0.f, 0.f, 0.f), s1 = s0, s2 = s0, s3 = s0;
    int ch = 0;
    for (; ch + 3 < nchunk; ch += 4) {
        const float4 a = src[idx + (size_t)(ch + 0) * cs];
        const float4 b = src[idx + (size_t)(ch + 1) * cs];
        const float4 c = src[idx + (size_t)(ch + 2) * cs];
        const float4 d = src[idx + (size_t)(ch + 3) * cs];
        s0.x += a.x; s0.y += a.y; s0.z += a.z; s0.w += a.w;
        s1.x += b.x; s1.y += b.y; s1.z += b.z; s1.w += b.w;
        s2.x += c.x; s2.y += c.y; s2.z += c.z; s2.w += c.w;
        s3.x += d.x; s3.y += d.y; s3.z += d.z; s3.w += d.w;
    }
    for (; ch < nchunk; ++ch) {
        const float4 a = src[idx + (size_t)ch * cs];
        s0.x += a.x; s0.y += a.y; s0.z += a.z; s0.w += a.w;
    }
    float4 r;
    r.x = (s0.x + s1.x) + (s2.x + s3.x);
    r.y = (s0.y + s1.y) + (s2.y + s3.y);
    r.z = (s0.z + s1.z) + (s2.z + s3.z);
    r.w = (s0.w + s1.w) + (s2.w + s3.w);
    reinterpret_cast<float4*>(W)[idx] = r;
}

// ---------------------------------------------------------------------------
// R2: per-feature epilogue on reduced W. wv = (S1 - c_sq*(B'+EPS))/B' (exact
// identity), entropy, neighbor repulsion, strict-upper Gram for inter.
// ---------------------------------------------------------------------------
__global__ __launch_bounds__(256) void epilogue_k(const float* __restrict__ W,
                                                  float* __restrict__ fpart) {
    __shared__ __align__(16) float Wl[32][CW];
    __shared__ float Bv[32], Binv[32], S1v[32], csq[32];
    __shared__ float scr[32][8];
    __shared__ float4 red4[256];
    const int t = threadIdx.x;
    const int f = blockIdx.x;

    for (int e = t; e < 32 * 33; e += 256) {
        const int k = e / 33, c4 = e % 33;
        reinterpret_cast<float4*>(Wl[k])[c4] =
            reinterpret_cast<const float4*>(W + (size_t)(f * 32 + k) * CW)[c4];
    }
    __syncthreads();
    if (t < 32) {
        const float B = Wl[t][129] + EPS_F;
        Bv[t] = B; Binv[t] = 1.0f / B; S1v[t] = Wl[t][128];
    }
    __syncthreads();
    {   // centroids in place + c_sq partials
        const int k = t >> 3, g = t & 7;
        const float ib = Binv[k];
        float s = 0.f;
        for (int c = g * 16; c < g * 16 + 16; ++c) {
            const float v = Wl[k][c] * ib;
            Wl[k][c] = v;
            s = fmaf(v, v, s);
        }
        scr[k][g] = s;
    }
    __syncthreads();
    if (t < 32) {
        float s = 0.f;
#pragma unroll
        for (int g = 0; g < 8; ++g) s += scr[t][g];
        csq[t] = s;
    }
    __syncthreads();

    float my_disp = 0.f, my_ent = 0.f, my_rep = 0.f, my_inter = 0.f;
    if (t < 32) {
        my_disp = (S1v[t] - csq[t] * (Bv[t] + EPS_F)) * Binv[t];
        const float p = Bv[t] * (1.0f / (float)N_PTS);
        my_ent = p * logf(p + EPS_F);
    }
    {   // neighbor repulsion
        const int pr = t >> 3, g = t & 7;
        float s = 0.f;
        if (pr < 31) {
            for (int c = g * 16; c < g * 16 + 16; ++c) {
                const float d = Wl[pr][c] - Wl[pr + 1][c];
                s = fmaf(d, d, s);
            }
        }
        __syncthreads();
        scr[pr][g] = s;
    }
    __syncthreads();
    if (t < 31) {
        float d = 0.f;
#pragma unroll
        for (int g = 0; g < 8; ++g) d += scr[t][g];
        my_rep = expf(-d);
    }
    // all-pairs inter (strict upper), float4 dots
#pragma unroll
    for (int s4 = 0; s4 < 4; ++s4) {
        const int slot = t + s4 * 256;
        const int k = slot >> 5, j = slot & 31;
        if (k < j) {
            float dot = 0.f;
            for (int c4 = 0; c4 < 32; ++c4) {
                const float4 a = reinterpret_cast<const float4*>(Wl[k])[c4];
                const float4 b = reinterpret_cast<const float4*>(Wl[j])[c4];
                dot = fmaf(a.x, b.x, dot); dot = fmaf(a.y, b.y, dot);
                dot = fmaf(a.z, b.z, dot); dot = fmaf(a.w, b.w, dot);
            }
            my_inter += expf(-(csq[k] + csq[j] - 2.0f * dot));
        }
    }
    red4[t] = make_float4(my_disp, my_ent, my_rep, my_inter);
    __syncthreads();
    for (int off = 128; off >= 1; off >>= 1) {
        if (t < off) {
            const float4 a = red4[t], b = red4[t + off];
            red4[t] = make_float4(a.x + b.x, a.y + b.y, a.z + b.z, a.w + b.w);
        }
        __syncthreads();
    }
    if (t == 0) {
        fpart[f * 4 + 0] = red4[0].x;
        fpart[f * 4 + 1] = red4[0].y;
        fpart[f * 4 + 2] = red4[0].z;
        fpart[f * 4 + 3] = red4[0].w;
    }
}

// ---------------------------------------------------------------------------
// K3: reduce 64 per-feature partials -> 5 scalar outputs
// ---------------------------------------------------------------------------
__global__ void final_reduce_k(const float* __restrict__ fpart,
                               float* __restrict__ out) {
    const int t = threadIdx.x;  // 64 threads
    float4 v = reinterpret_cast<const float4*>(fpart)[t];
#pragma unroll
    for (int m = 32; m >= 1; m >>= 1) {
        v.x += __shfl_xor(v.x, m, 64);
        v.y += __shfl_xor(v.y, m, 64);
        v.z += __shfl_xor(v.z, m, 64);
        v.w += __shfl_xor(v.w, m, 64);
    }
    if (t == 0) {
        const float disp  = v.x, ent = v.y, rep = v.z;
        const float inter = v.w * (1.0f / (float)F_DIM);
        out[0] = disp + 0.1f * ent + 0.5f * rep + 0.3f * inter;
        out[1] = disp;
        out[2] = ent;
        out[3] = rep;
        out[4] = inter;
    }
}

extern "C" void kernel_launch(void* const* d_in, const int* in_sizes, int n_in,
                              void* d_out, int out_size, void* d_ws, size_t ws_size,
                              hipStream_t stream) {
    const float* M = (const float*)d_in[0];   // (16384, 64, 32) fp32
    const float* Y = (const float*)d_in[1];   // (16384, 128) fp32
    float* out = (float*)d_out;               // 5 floats
    char*  ws  = (char*)d_ws;

    const size_t ytBytes = (size_t)CP * N_PTS * sizeof(_Float16);  // 4,718,592
    const size_t wBytes  = (size_t)FK * CW * sizeof(float);        // 1,081,344

    _Float16* Yt    = (_Float16*)ws;
    float*    W     = (float*)(ws + ytBytes);
    float*    fpart = (float*)(ws + ytBytes + wBytes);
    float*    wpart = (float*)(ws + ytBytes + wBytes + 1024);

    const size_t used = ytBytes + wBytes + 1024;
    int nchunk = 32;    // split-K factor -> 32 x 32 = 1024 blocks (4/CU)
    while (nchunk > 1 && used + (size_t)nchunk * wBytes > ws_size) nchunk >>= 1;
    const int cn = N_PTS / nchunk;   // multiple of 64

    build_yt_k<<<dim3(N_PTS / 64), dim3(256), 0, stream>>>(Y, Yt);
    gemm_k<<<dim3(32, nchunk), dim3(256), 0, stream>>>(M, Yt, wpart, cn);
    reduce_w_k<<<dim3(FK * CW / 4 / 128), dim3(128), 0, stream>>>(wpart, W, nchunk);
    epilogue_k<<<dim3(F_DIM), dim3(256), 0, stream>>>(W, fpart);
    final_reduce_k<<<dim3(1), dim3(64), 0, stream>>>(fpart, out);
}

// Round 5
// 233.649 us; speedup vs baseline: 1.1554x; 1.1554x over previous
//
#include <hip/hip_runtime.h>
#include <math.h>

#define N_PTS   16384
#define F_DIM   64
#define K_BINS  32
#define C_DIM   128
#define FK      2048      // F*K
#define NB32    (N_PTS / 32)   // 512 n-blocks of 32
#define CW      132       // W row stride: [w0..w127, S1, B, pad0, pad0]
#define EPS_F   1e-8f

typedef _Float16 f16x8 __attribute__((ext_vector_type(8)));
typedef float    f32x4 __attribute__((ext_vector_type(4)));

// ---------------------------------------------------------------------------
// K0: build Ybf — Y' transposed AND pre-blocked into MFMA B-fragment order.
//   Y'[n][c]: c 0..127 = teacher, 128 = y_sq, 129 = 1, 130..143 = 0.
//   Ybf[((ct*NB32 + nb)*64 + l)*8 + j] = Y'[nb*32 + (l>>4)*8 + j][ct*16 + (l&15)]
// so a wave's B-tile for (ct, nb) is ONE dense 1024 B block, lane-ordered.
// One block per 64 n (2 nb). Coalesced Y read via LDS tile, coalesced
// dwordx4 Ybf writes.
// ---------------------------------------------------------------------------
__global__ __launch_bounds__(256) void build_ybf_k(const float* __restrict__ Y,
                                                   _Float16* __restrict__ Ybf) {
    __shared__ __align__(16) float Yl[64][132];
    __shared__ float ysql[64];
    const int t  = threadIdx.x;
    const int n0 = blockIdx.x * 64;
    const int nl = t >> 5;        // 0..7
    const int c4 = t & 31;
#pragma unroll
    for (int p = 0; p < 8; ++p) {
        const int n = p * 8 + nl;
        const float4 v = reinterpret_cast<const float4*>(Y + (size_t)(n0 + n) * C_DIM)[c4];
        reinterpret_cast<float4*>(Yl[n])[c4] = v;
        float sq = v.x * v.x + v.y * v.y + v.z * v.z + v.w * v.w;
#pragma unroll
        for (int m = 16; m >= 1; m >>= 1) sq += __shfl_xor(sq, m, 64);
        if (c4 == 0) ysql[n] = sq;
    }
    __syncthreads();
    // compose 1152 fragment-slots: (nb2, ct, l)
    for (int p = 0; p < 5; ++p) {
        const int s = t + p * 256;
        if (s < 1152) {
            const int nb2  = s / 576;
            const int r    = s % 576;
            const int ct   = r >> 6;
            const int l    = r & 63;
            const int quad = l >> 4, cl = l & 15;
            const int nloc = nb2 * 32 + quad * 8;
            f16x8 v;
            if (ct < 8) {
                const int c = ct * 16 + cl;
#pragma unroll
                for (int j = 0; j < 8; ++j) v[j] = (_Float16)Yl[nloc + j][c];
            } else if (cl == 0) {
#pragma unroll
                for (int j = 0; j < 8; ++j) v[j] = (_Float16)ysql[nloc + j];
            } else if (cl == 1) {
#pragma unroll
                for (int j = 0; j < 8; ++j) v[j] = (_Float16)1.0f;
            } else {
#pragma unroll
                for (int j = 0; j < 8; ++j) v[j] = (_Float16)0.0f;
            }
            const int nb = blockIdx.x * 2 + nb2;
            *reinterpret_cast<f16x8*>(Ybf + ((size_t)(ct * NB32 + nb) * 64 + l) * 8) = v;
        }
    }
}

// ---------------------------------------------------------------------------
// K1: split-K MFMA GEMM. wpart[ch][fk][c] = sum_{n in chunk} M[n][fk]*Y'[n][c]
// Block 256 thr = 4 waves, fk-tile 64 (wave w owns 16 fk), 9 c-tiles.
// Per 32-n step: B-tile (9 KB, dense) staged into double-buffered LDS via
// global_load_lds width=16 (fragment layout == wave-uniform base + lane*16
// by construction), shared by all 4 waves; A gathered from global M
// (register-pipelined 2 steps ahead; 4x64B dense segments per load; M read
// exactly once from HBM). m97-style 2-barrier step; 1024 blocks = 4/CU so
// barrier-drain stalls overlap across blocks.
// ---------------------------------------------------------------------------
__global__ __launch_bounds__(256) void gemm_k(const float* __restrict__ M,
                                              const _Float16* __restrict__ Ybf,
                                              float* __restrict__ wpart,
                                              int cn) {
    __shared__ __align__(16) _Float16 Bb[2][9][512];   // 2 x 9 KB
    const int t    = threadIdx.x;
    const int fk0  = blockIdx.x * 64;
    const int ch   = blockIdx.y;
    const int n0   = ch * cn;
    const int nb0  = n0 >> 5;
    const int w    = t >> 6;
    const int l    = t & 63;
    const int quad = l >> 4;
    const int cl   = l & 15;
    const int fkA  = fk0 + w * 16 + cl;
    const float* mp = M + fkA;
    const int steps = cn >> 5;            // even (cn multiple of 64)

    f32x4 acc[9] = {};
    float a0r[8], a1r[8];

#define STAGE(s, par)                                                          \
    {                                                                          \
        const int nb_ = nb0 + (s);                                             \
        _Pragma("unroll")                                                      \
        for (int ct = w; ct < 9; ct += 4) {                                    \
            const _Float16* g_ = Ybf + ((size_t)(ct * NB32 + nb_) * 64 + l) * 8; \
            __builtin_amdgcn_global_load_lds(                                  \
                (const __attribute__((address_space(1))) unsigned*)g_,         \
                (__attribute__((address_space(3))) unsigned*)&Bb[par][ct][0],  \
                16, 0, 0);                                                     \
        }                                                                      \
    }
#define LOADA(ar, s)                                                           \
    {                                                                          \
        const size_t nbase_ = (size_t)(n0 + (s) * 32 + quad * 8);              \
        _Pragma("unroll")                                                      \
        for (int j = 0; j < 8; ++j) ar[j] = mp[(nbase_ + j) * FK];             \
    }

    STAGE(0, 0); LOADA(a0r, 0);
    STAGE(1, 1); LOADA(a1r, 1);

    for (int s = 0; s < steps; s += 2) {
        // ---- even step: buf 0 ----
        __syncthreads();                    // stage(s) landed in LDS
        {
            f16x8 bf[9];
#pragma unroll
            for (int ct = 0; ct < 9; ++ct)
                bf[ct] = *reinterpret_cast<const f16x8*>(&Bb[0][ct][l * 8]);
            f16x8 af;
#pragma unroll
            for (int j = 0; j < 8; ++j) af[j] = (_Float16)a0r[j];
            __syncthreads();                // all waves done reading buf0
            if (s + 2 < steps) { STAGE(s + 2, 0); LOADA(a0r, s + 2); }
#pragma unroll
            for (int ct = 0; ct < 9; ++ct)
                acc[ct] = __builtin_amdgcn_mfma_f32_16x16x32_f16(af, bf[ct], acc[ct], 0, 0, 0);
        }
        // ---- odd step: buf 1 ----
        __syncthreads();                    // stage(s+1) landed in LDS
        {
            f16x8 bf[9];
#pragma unroll
            for (int ct = 0; ct < 9; ++ct)
                bf[ct] = *reinterpret_cast<const f16x8*>(&Bb[1][ct][l * 8]);
            f16x8 af;
#pragma unroll
            for (int j = 0; j < 8; ++j) af[j] = (_Float16)a1r[j];
            __syncthreads();                // all waves done reading buf1
            if (s + 3 < steps) { STAGE(s + 3, 1); LOADA(a1r, s + 3); }
#pragma unroll
            for (int ct = 0; ct < 9; ++ct)
                acc[ct] = __builtin_amdgcn_mfma_f32_16x16x32_f16(af, bf[ct], acc[ct], 0, 0, 0);
        }
    }
#undef STAGE
#undef LOADA

    // D layout: col(c) = lane&15, row(fk) = quad*4 + reg
    float* wp = wpart + (size_t)ch * FK * CW;
#pragma unroll
    for (int ct = 0; ct < 9; ++ct) {
        const int c = ct * 16 + cl;
        if (c < CW) {
#pragma unroll
            for (int r = 0; r < 4; ++r) {
                const int fk = fk0 + w * 16 + quad * 4 + r;
                wp[(size_t)fk * CW + c] = acc[ct][r];
            }
        }
    }
}

// ---------------------------------------------------------------------------
// R1: chunk reduction wpart -> W. 528 blocks x 128 thr, 4-way ILP over chunks.
// ---------------------------------------------------------------------------
__global__ __launch_bounds__(128) void reduce_w_k(const float* __restrict__ wpart,
                                                  float* __restrict__ W, int nchunk) {
    const int idx = blockIdx.x * 128 + threadIdx.x;   // float4 index, grid exact
    const float4* src = reinterpret_cast<const float4*>(wpart);
    const size_t cs = (size_t)FK * CW / 4;
    float4 s0 = make_float4(0.f, 0.f, 0.f, 0.f), s1 = s0, s2 = s0, s3 = s0;
    int ch = 0;
    for (; ch + 3 < nchunk; ch += 4) {
        const float4 a = src[idx + (size_t)(ch + 0) * cs];
        const float4 b = src[idx + (size_t)(ch + 1) * cs];
        const float4 c = src[idx + (size_t)(ch + 2) * cs];
        const float4 d = src[idx + (size_t)(ch + 3) * cs];
        s0.x += a.x; s0.y += a.y; s0.z += a.z; s0.w += a.w;
        s1.x += b.x; s1.y += b.y; s1.z += b.z; s1.w += b.w;
        s2.x += c.x; s2.y += c.y; s2.z += c.z; s2.w += c.w;
        s3.x += d.x; s3.y += d.y; s3.z += d.z; s3.w += d.w;
    }
    for (; ch < nchunk; ++ch) {
        const float4 a = src[idx + (size_t)ch * cs];
        s0.x += a.x; s0.y += a.y; s0.z += a.z; s0.w += a.w;
    }
    float4 r;
    r.x = (s0.x + s1.x) + (s2.x + s3.x);
    r.y = (s0.y + s1.y) + (s2.y + s3.y);
    r.z = (s0.z + s1.z) + (s2.z + s3.z);
    r.w = (s0.w + s1.w) + (s2.w + s3.w);
    reinterpret_cast<float4*>(W)[idx] = r;
}

// ---------------------------------------------------------------------------
// R2: per-feature epilogue on reduced W. wv = (S1 - c_sq*(B'+EPS))/B' (exact
// identity), entropy, neighbor repulsion, strict-upper Gram for inter.
// ---------------------------------------------------------------------------
__global__ __launch_bounds__(256) void epilogue_k(const float* __restrict__ W,
                                                  float* __restrict__ fpart) {
    __shared__ __align__(16) float Wl[32][CW];
    __shared__ float Bv[32], Binv[32], S1v[32], csq[32];
    __shared__ float scr[32][8];
    __shared__ float4 red4[256];
    const int t = threadIdx.x;
    const int f = blockIdx.x;

    for (int e = t; e < 32 * 33; e += 256) {
        const int k = e / 33, c4 = e % 33;
        reinterpret_cast<float4*>(Wl[k])[c4] =
            reinterpret_cast<const float4*>(W + (size_t)(f * 32 + k) * CW)[c4];
    }
    __syncthreads();
    if (t < 32) {
        const float B = Wl[t][129] + EPS_F;
        Bv[t] = B; Binv[t] = 1.0f / B; S1v[t] = Wl[t][128];
    }
    __syncthreads();
    {   // centroids in place + c_sq partials
        const int k = t >> 3, g = t & 7;
        const float ib = Binv[k];
        float s = 0.f;
        for (int c = g * 16; c < g * 16 + 16; ++c) {
            const float v = Wl[k][c] * ib;
            Wl[k][c] = v;
            s = fmaf(v, v, s);
        }
        scr[k][g] = s;
    }
    __syncthreads();
    if (t < 32) {
        float s = 0.f;
#pragma unroll
        for (int g = 0; g < 8; ++g) s += scr[t][g];
        csq[t] = s;
    }
    __syncthreads();

    float my_disp = 0.f, my_ent = 0.f, my_rep = 0.f, my_inter = 0.f;
    if (t < 32) {
        my_disp = (S1v[t] - csq[t] * (Bv[t] + EPS_F)) * Binv[t];
        const float p = Bv[t] * (1.0f / (float)N_PTS);
        my_ent = p * logf(p + EPS_F);
    }
    {   // neighbor repulsion
        const int pr = t >> 3, g = t & 7;
        float s = 0.f;
        if (pr < 31) {
            for (int c = g * 16; c < g * 16 + 16; ++c) {
                const float d = Wl[pr][c] - Wl[pr + 1][c];
                s = fmaf(d, d, s);
            }
        }
        __syncthreads();
        scr[pr][g] = s;
    }
    __syncthreads();
    if (t < 31) {
        float d = 0.f;
#pragma unroll
        for (int g = 0; g < 8; ++g) d += scr[t][g];
        my_rep = expf(-d);
    }
    // all-pairs inter (strict upper), float4 dots
#pragma unroll
    for (int s4 = 0; s4 < 4; ++s4) {
        const int slot = t + s4 * 256;
        const int k = slot >> 5, j = slot & 31;
        if (k < j) {
            float dot = 0.f;
            for (int c4 = 0; c4 < 32; ++c4) {
                const float4 a = reinterpret_cast<const float4*>(Wl[k])[c4];
                const float4 b = reinterpret_cast<const float4*>(Wl[j])[c4];
                dot = fmaf(a.x, b.x, dot); dot = fmaf(a.y, b.y, dot);
                dot = fmaf(a.z, b.z, dot); dot = fmaf(a.w, b.w, dot);
            }
            my_inter += expf(-(csq[k] + csq[j] - 2.0f * dot));
        }
    }
    red4[t] = make_float4(my_disp, my_ent, my_rep, my_inter);
    __syncthreads();
    for (int off = 128; off >= 1; off >>= 1) {
        if (t < off) {
            const float4 a = red4[t], b = red4[t + off];
            red4[t] = make_float4(a.x + b.x, a.y + b.y, a.z + b.z, a.w + b.w);
        }
        __syncthreads();
    }
    if (t == 0) {
        fpart[f * 4 + 0] = red4[0].x;
        fpart[f * 4 + 1] = red4[0].y;
        fpart[f * 4 + 2] = red4[0].z;
        fpart[f * 4 + 3] = red4[0].w;
    }
}

// ---------------------------------------------------------------------------
// K3: reduce 64 per-feature partials -> 5 scalar outputs
// ---------------------------------------------------------------------------
__global__ void final_reduce_k(const float* __restrict__ fpart,
                               float* __restrict__ out) {
    const int t = threadIdx.x;  // 64 threads
    float4 v = reinterpret_cast<const float4*>(fpart)[t];
#pragma unroll
    for (int m = 32; m >= 1; m >>= 1) {
        v.x += __shfl_xor(v.x, m, 64);
        v.y += __shfl_xor(v.y, m, 64);
        v.z += __shfl_xor(v.z, m, 64);
        v.w += __shfl_xor(v.w, m, 64);
    }
    if (t == 0) {
        const float disp  = v.x, ent = v.y, rep = v.z;
        const float inter = v.w * (1.0f / (float)F_DIM);
        out[0] = disp + 0.1f * ent + 0.5f * rep + 0.3f * inter;
        out[1] = disp;
        out[2] = ent;
        out[3] = rep;
        out[4] = inter;
    }
}

extern "C" void kernel_launch(void* const* d_in, const int* in_sizes, int n_in,
                              void* d_out, int out_size, void* d_ws, size_t ws_size,
                              hipStream_t stream) {
    const float* M = (const float*)d_in[0];   // (16384, 64, 32) fp32
    const float* Y = (const float*)d_in[1];   // (16384, 128) fp32
    float* out = (float*)d_out;               // 5 floats
    char*  ws  = (char*)d_ws;

    const size_t ybfBytes = (size_t)9 * NB32 * 64 * 8 * sizeof(_Float16);  // 4,718,592
    const size_t wBytes   = (size_t)FK * CW * sizeof(float);               // 1,081,344

    _Float16* Ybf   = (_Float16*)ws;
    float*    W     = (float*)(ws + ybfBytes);
    float*    fpart = (float*)(ws + ybfBytes + wBytes);
    float*    wpart = (float*)(ws + ybfBytes + wBytes + 1024);

    const size_t used = ybfBytes + wBytes + 1024;
    int nchunk = 32;    // split-K -> 32 x 32 = 1024 blocks (4/CU)
    while (nchunk > 1 && used + (size_t)nchunk * wBytes > ws_size) nchunk >>= 1;
    const int cn = N_PTS / nchunk;   // multiple of 64

    build_ybf_k<<<dim3(N_PTS / 64), dim3(256), 0, stream>>>(Y, Ybf);
    gemm_k<<<dim3(32, nchunk), dim3(256), 0, stream>>>(M, Ybf, wpart, cn);
    reduce_w_k<<<dim3(FK * CW / 4 / 128), dim3(128), 0, stream>>>(wpart, W, nchunk);
    epilogue_k<<<dim3(F_DIM), dim3(256), 0, stream>>>(W, fpart);
    final_reduce_k<<<dim3(1), dim3(64), 0, stream>>>(fpart, out);
}